// Round 12
// baseline (538.432 us; speedup 1.0000x reference)
//
#include <hip/hip_runtime.h>
#include <math.h>

#define E_TOT 262144
#define N_SRC 16384
#define LDIM  128
#define MIN_VARF 0.001f
#define INV_SQRT2PIF 0.3989422804014327f
#define EPB   128            // edges per block (4 waves x 32)
#define NBLK  (E_TOT / EPB)  // 2048

typedef _Float16 half8  __attribute__((ext_vector_type(8)));
typedef __fp16   fp16x2 __attribute__((ext_vector_type(2)));
typedef float    f32x4  __attribute__((ext_vector_type(4)));
typedef float    f32x2  __attribute__((ext_vector_type(2)));
typedef unsigned int uint2v __attribute__((ext_vector_type(2)));

// ---- d_ws byte layout ----
#define BIAS_OFF  256        // 3 layers x 128 f32 (reordered [g*32+t*4+r])
#define WOUT_OFF  1792       // 2 x 128 f32
#define BOUT_OFF  2816       // 1 f32
#define PART_OFF  4096       // NBLK x f32x2 -> 16 KB
#define PK_L0     36864      // 40960 -> 77824
#define PK_L1     77824      // 32768 -> 110592
#define PK_L2     110592     // 32768 -> 143360
#define LAT16_OFF 143360     // 4 MB
#define VAR16_OFF 4337664    // 4 MB
#define WS_NEED   8531968

__device__ __forceinline__ unsigned int pkrtz(float a, float b) {
    union { fp16x2 h; unsigned int u; } z;
    z.h = __builtin_amdgcn_cvt_pkrtz(a, b);
    return z.u;
}
__device__ __forceinline__ half8 to_h8(f32x4 a, f32x4 b) {
    union { half8 h; unsigned int u[4]; } z;
    z.u[0] = pkrtz(a[0], a[1]); z.u[1] = pkrtz(a[2], a[3]);
    z.u[2] = pkrtz(b[0], b[1]); z.u[3] = pkrtz(b[2], b[3]);
    return z.h;
}
__device__ __forceinline__ half8 ch_to_h8(uint2v lo, uint2v hi) {
    union { half8 h; unsigned int u[4]; } z;
    z.u[0] = lo[0]; z.u[1] = lo[1]; z.u[2] = hi[0]; z.u[3] = hi[1];
    return z.h;
}

// ADF-ReLU with A&S 7.1.26 erf sharing the pdf's exp(-r^2/2). 3 trans total.
__device__ __forceinline__ void adf_relu(float& m, float& v) {
    float vv = fmaxf(v, 1e-6f);
    float is = __builtin_amdgcn_rsqf(vv);    // 1/sd
    float sd = vv * is;
    float r  = m * is;
    float qq = 0.5f * r * r;
    float e  = __expf(-qq);
    float sp = sd * e * INV_SQRT2PIF;        // sd * pdf
    const float P = 0.23165247f;             // 0.3275911 / sqrt(2)
    float t  = __builtin_amdgcn_rcpf(fmaf(fabsf(r), P, 1.0f));
    float poly = t * fmaf(t, fmaf(t, fmaf(t, fmaf(t, 1.061405429f, -1.453152027f),
                                          1.421413741f), -0.284496736f), 0.254829592f);
    float erfa = fmaf(-poly, e, 1.0f);
    float cdf  = fmaf(copysignf(0.5f, r), erfa, 0.5f);
    float mo = fmaf(m, cdf, sp);
    float vo = fmaf(fmaf(m, m, vv), cdf, fmaf(m, sp, -mo * mo));
    m = mo; v = vo;
}

// Pack latents/var f32 -> f16 (RTE) into ws.
__global__ void prep_pack(const float* __restrict__ latents, const float* __restrict__ varr,
                          char* __restrict__ ws)
{
    int idx = blockIdx.x * 256 + threadIdx.x;          // [0, 524288)
    const int half = idx >> 18;
    const int j    = idx & 262143;
    const float* src = (half ? varr : latents) + (long)j * 8;
    char* dst = ws + (half ? VAR16_OFF : LAT16_OFF) + (long)j * 16;
    f32x4 a = *(const f32x4*)(src);
    f32x4 b = *(const f32x4*)(src + 4);
    half8 hv;
#pragma unroll
    for (int k = 0; k < 4; ++k) { hv[k] = (_Float16)a[k]; hv[k + 4] = (_Float16)b[k]; }
    *(half8*)dst = hv;
}

// Pack weights fragment-linear f16.
// L0 (linear K): entry (ks,t,lane): A[16t+(lane&15)][32ks+8*(lane>>4)+j]
// L1/L2 (PERMUTED K so prev-layer acc registers ARE the B-frag):
//   pos = 32ks+8g+j  ->  k = 16*(2ks+(j>=4)) + 4g + (j&3)
__global__ void prep(const float* __restrict__ W_in, const float* __restrict__ b_in,
                     const float* __restrict__ W1,   const float* __restrict__ b1,
                     const float* __restrict__ W2,   const float* __restrict__ b2,
                     const float* __restrict__ W_out,const float* __restrict__ b_out,
                     char* __restrict__ ws)
{
    int idx = blockIdx.x * 256 + threadIdx.x;
    if (idx < 6656) {
        const float* W; long dstoff; int entry; bool lin;
        if (idx < 2560)      { entry = idx;        W = W_in; dstoff = PK_L0; lin = true;  }
        else if (idx < 4608) { entry = idx - 2560; W = W1;   dstoff = PK_L1; lin = false; }
        else                 { entry = idx - 4608; W = W2;   dstoff = PK_L2; lin = false; }
        int ks   = entry >> 9;
        int rest = entry & 511;
        int t    = rest >> 6;
        int lane = rest & 63;
        int rowi = t * 16 + (lane & 15);
        int gp   = lane >> 4;
        half8 hv;
        if (lin) {
            int k0 = ks * 32 + gp * 8;
#pragma unroll
            for (int j = 0; j < 8; ++j) {
                int k = k0 + j;
                hv[j] = (_Float16)((k < 131) ? W[rowi * 131 + k] : 0.0f);
            }
        } else {
#pragma unroll
            for (int j = 0; j < 8; ++j) {
                int k = (2 * ks + (j >= 4 ? 1 : 0)) * 16 + 4 * gp + (j & 3);
                hv[j] = (_Float16)W[rowi * 128 + k];
            }
        }
        *(half8*)(ws + dstoff + (long)entry * 16) = hv;
    } else if (idx < 6656 + 384) {
        int j = idx - 6656; int layer = j >> 7; int pidx = j & 127;
        int gg = pidx >> 5, t = (pidx >> 2) & 7, r = pidx & 3;
        int n = t * 16 + gg * 4 + r;
        const float* b = layer == 0 ? b_in : (layer == 1 ? b1 : b2);
        ((float*)(ws + BIAS_OFF))[layer * 128 + pidx] = b[n];
    } else if (idx < 6656 + 384 + 256) {
        int j = idx - 6656 - 384; int path = j >> 7; int pidx = j & 127;
        int gg = pidx >> 5, t = (pidx >> 2) & 7, r = pidx & 3;
        int n = t * 16 + gg * 4 + r;
        float v = W_out[n];
        if (path) v = v * v;
        ((float*)(ws + WOUT_OFF))[path * 128 + pidx] = v;
    } else if (idx == 6656 + 384 + 256) {
        ((float*)(ws + BOUT_OFF))[0] = b_out[0];
    }
}

// epilogue: bias + ADF-ReLU, pack f16 chunks (registers, no LDS)
__device__ __forceinline__ void epi_reg(const f32x4* am, const f32x4* av, const f32x4* bp,
                                        uint2v* chm, uint2v* chv)
{
#pragma unroll
    for (int t = 0; t < 8; ++t) {
        f32x4 b4 = bp[t];
        float m0 = am[t][0] + b4[0], m1 = am[t][1] + b4[1];
        float m2 = am[t][2] + b4[2], m3 = am[t][3] + b4[3];
        float v0 = av[t][0], v1 = av[t][1], v2 = av[t][2], v3 = av[t][3];
        adf_relu(m0, v0); adf_relu(m1, v1); adf_relu(m2, v2); adf_relu(m3, v3);
        uint2v sm = {pkrtz(m0, m1), pkrtz(m2, m3)};
        uint2v sv = {pkrtz(v0, v1), pkrtz(v2, v3)};
        chm[t] = sm; chv[t] = sv;
    }
}

template <bool PACKED>
__global__ void __launch_bounds__(256, 4)
interp_main(const float* __restrict__ pos_source, const float* __restrict__ pos_target,
            const float* __restrict__ latents,    const float* __restrict__ varr,
            const float* __restrict__ drop_mask,
            const int* __restrict__ row, const int* __restrict__ col, const int* __restrict__ occ,
            float* __restrict__ out, char* __restrict__ ws)
{
    __shared__ float wred[4][2];

    const int tid  = threadIdx.x;
    const int lane = tid & 63;
    const int w    = tid >> 6;
    const int q    = lane & 15;
    const int g    = lane >> 4;
    const int g8   = g * 8;
    const int er0  = w * 32 + q;
    const int er1  = er0 + 16;
    const int ge0  = blockIdx.x * EPB + er0;
    const int ge1  = ge0 + 16;

    const int c0 = col[ge0], c1 = col[ge1];
    const int r0 = row[ge0], r1 = row[ge1];
    const float occf0 = (float)occ[r0];
    const float occf1 = (float)occ[r1];
    const float px0 = pos_target[r0 * 3 + 0] - pos_source[c0 * 3 + 0];
    const float py0 = pos_target[r0 * 3 + 1] - pos_source[c0 * 3 + 1];
    const float pz0 = pos_target[r0 * 3 + 2] - pos_source[c0 * 3 + 2];
    const float px1 = pos_target[r1 * 3 + 0] - pos_source[c1 * 3 + 0];
    const float py1 = pos_target[r1 * 3 + 1] - pos_source[c1 * 3 + 1];
    const float pz1 = pos_target[r1 * 3 + 2] - pos_source[c1 * 3 + 2];

    f32x4 acm0[8], acv0[8], acm1[8], acv1[8];
    const f32x4 zz = {0.0f, 0.0f, 0.0f, 0.0f};
#pragma unroll
    for (int t = 0; t < 8; ++t) { acm0[t] = zz; acv0[t] = zz; acm1[t] = zz; acv1[t] = zz; }

    uint2v chm0[8], chv0[8], chm1[8], chv1[8];

    // ================= layer 0: B from packed f16 latents, A shared across 2 edges =====
    {
        const char* pk = ws + PK_L0 + lane * 16;
#pragma unroll
        for (int ks = 0; ks < 4; ++ks) {
            half8 bm0, bv0, bm1, bv1;
            if (PACKED) {
                const long o0 = (long)c0 * 256 + ks * 64 + g8 * 2;
                const long o1 = (long)c1 * 256 + ks * 64 + g8 * 2;
                bm0 = *(const half8*)(ws + LAT16_OFF + o0);
                bv0 = *(const half8*)(ws + VAR16_OFF + o0);
                bm1 = *(const half8*)(ws + LAT16_OFF + o1);
                bv1 = *(const half8*)(ws + VAR16_OFF + o1);
            } else {
                const f32x4* a0 = (const f32x4*)(latents + (long)c0 * LDIM + ks * 32 + g8);
                const f32x4* s0 = (const f32x4*)(varr    + (long)c0 * LDIM + ks * 32 + g8);
                const f32x4* a1 = (const f32x4*)(latents + (long)c1 * LDIM + ks * 32 + g8);
                const f32x4* s1 = (const f32x4*)(varr    + (long)c1 * LDIM + ks * 32 + g8);
                bm0 = to_h8(a0[0], a0[1]); bv0 = to_h8(s0[0], s0[1]);
                bm1 = to_h8(a1[0], a1[1]); bv1 = to_h8(s1[0], s1[1]);
            }
            const char* pmk = pk + ks * 8192;
#pragma unroll
            for (int t = 0; t < 8; ++t) {
                half8 am = *(const half8*)(pmk + t * 1024);
                half8 av = am * am;
                acm0[t] = __builtin_amdgcn_mfma_f32_16x16x32_f16(am, bm0, acm0[t], 0, 0, 0);
                acm1[t] = __builtin_amdgcn_mfma_f32_16x16x32_f16(am, bm1, acm1[t], 0, 0, 0);
                acv0[t] = __builtin_amdgcn_mfma_f32_16x16x32_f16(av, bv0, acv0[t], 0, 0, 0);
                acv1[t] = __builtin_amdgcn_mfma_f32_16x16x32_f16(av, bv1, acv1[t], 0, 0, 0);
            }
        }
        // ks = 4: pos_rel (k = 128..130)
        half8 bp0 = {(_Float16)0.f, (_Float16)0.f, (_Float16)0.f, (_Float16)0.f,
                     (_Float16)0.f, (_Float16)0.f, (_Float16)0.f, (_Float16)0.f};
        half8 bp1 = bp0;
        if (g == 0) {
            bp0[0] = (_Float16)px0; bp0[1] = (_Float16)py0; bp0[2] = (_Float16)pz0;
            bp1[0] = (_Float16)px1; bp1[1] = (_Float16)py1; bp1[2] = (_Float16)pz1;
        }
        const char* pmk = pk + 4 * 8192;
#pragma unroll
        for (int t = 0; t < 8; ++t) {
            half8 am = *(const half8*)(pmk + t * 1024);
            half8 av = am * am;
            acm0[t] = __builtin_amdgcn_mfma_f32_16x16x32_f16(am, bp0, acm0[t], 0, 0, 0);
            acm1[t] = __builtin_amdgcn_mfma_f32_16x16x32_f16(am, bp1, acm1[t], 0, 0, 0);
            acv0[t] = __builtin_amdgcn_mfma_f32_16x16x32_f16(av, bp0, acv0[t], 0, 0, 0);
            acv1[t] = __builtin_amdgcn_mfma_f32_16x16x32_f16(av, bp1, acv1[t], 0, 0, 0);
        }
        const f32x4* bp = (const f32x4*)(ws + BIAS_OFF) + g8;
        epi_reg(acm0, acv0, bp, chm0, chv0);
        epi_reg(acm1, acv1, bp, chm1, chv1);
    }

    // ================= layers 1,2: B from prev acc registers (permuted W), A shared ====
#pragma unroll
    for (int layer = 1; layer < 3; ++layer) {
        const char* pk = ws + (layer == 1 ? PK_L1 : PK_L2) + lane * 16;
#pragma unroll
        for (int t = 0; t < 8; ++t) { acm0[t] = zz; acv0[t] = zz; acm1[t] = zz; acv1[t] = zz; }
#pragma unroll
        for (int ks = 0; ks < 4; ++ks) {
            half8 bm0 = ch_to_h8(chm0[2 * ks], chm0[2 * ks + 1]);
            half8 bv0 = ch_to_h8(chv0[2 * ks], chv0[2 * ks + 1]);
            half8 bm1 = ch_to_h8(chm1[2 * ks], chm1[2 * ks + 1]);
            half8 bv1 = ch_to_h8(chv1[2 * ks], chv1[2 * ks + 1]);
            const char* pmk = pk + ks * 8192;
#pragma unroll
            for (int t = 0; t < 8; ++t) {
                half8 am = *(const half8*)(pmk + t * 1024);
                half8 av = am * am;
                acm0[t] = __builtin_amdgcn_mfma_f32_16x16x32_f16(am, bm0, acm0[t], 0, 0, 0);
                acm1[t] = __builtin_amdgcn_mfma_f32_16x16x32_f16(am, bm1, acm1[t], 0, 0, 0);
                acv0[t] = __builtin_amdgcn_mfma_f32_16x16x32_f16(av, bv0, acv0[t], 0, 0, 0);
                acv1[t] = __builtin_amdgcn_mfma_f32_16x16x32_f16(av, bv1, acv1[t], 0, 0, 0);
            }
        }
        if (layer == 1) {
            const f32x4* bp = (const f32x4*)(ws + BIAS_OFF) + 32 + g8;
            epi_reg(acm0, acv0, bp, chm0, chv0);
            epi_reg(acm1, acv1, bp, chm1, chv1);
        }
    }

    // ================= final epilogue: dropout + W_out dot + reductions =================
    {
        const f32x4* wmp = (const f32x4*)(ws + WOUT_OFF);
        const f32x4* bp  = (const f32x4*)(ws + BIAS_OFF) + 64 + g8;
        const f32x4* dm0 = (const f32x4*)(drop_mask + (size_t)ge0 * LDIM) + g;
        const f32x4* dm1 = (const f32x4*)(drop_mask + (size_t)ge1 * LDIM) + g;
        float pm0 = 0.f, pv0 = 0.f, pm1 = 0.f, pv1 = 0.f;
#pragma unroll
        for (int t = 0; t < 8; ++t) {
            f32x4 b4 = bp[t];
            f32x4 w4 = wmp[g8 + t];
            f32x4 s4 = wmp[32 + g8 + t];
            f32x4 d0 = __builtin_nontemporal_load(dm0 + t * 4);
            f32x4 d1 = __builtin_nontemporal_load(dm1 + t * 4);
#pragma unroll
            for (int j = 0; j < 4; ++j) {
                float m0 = (acm0[t][j] + b4[j]) * d0[j];
                float v0 = acv0[t][j] * d0[j] * d0[j] + MIN_VARF;
                float m1 = (acm1[t][j] + b4[j]) * d1[j];
                float v1 = acv1[t][j] * d1[j] * d1[j] + MIN_VARF;
                pm0 = fmaf(w4[j], m0, pm0); pv0 = fmaf(s4[j], v0, pv0);
                pm1 = fmaf(w4[j], m1, pm1); pv1 = fmaf(s4[j], v1, pv1);
            }
        }
        pm0 += __shfl_xor(pm0, 16, 64); pm0 += __shfl_xor(pm0, 32, 64);
        pv0 += __shfl_xor(pv0, 16, 64); pv0 += __shfl_xor(pv0, 32, 64);
        pm1 += __shfl_xor(pm1, 16, 64); pm1 += __shfl_xor(pm1, 32, 64);
        pv1 += __shfl_xor(pv1, 16, 64); pv1 += __shfl_xor(pv1, 32, 64);
        float bout = *(const float*)(ws + BOUT_OFF);
        float p0 = pm0 + bout;
        float p1 = pm1 + bout;
        if (lane < 16) {
            out[ge0] = p0;            out[ge1] = p1;
            out[E_TOT + 2 + ge0] = occf0;
            out[E_TOT + 2 + ge1] = occf1;
        }
        float a0 = fabsf(p0), a1 = fabsf(p1);
        float loss = fmaxf(p0, 0.f) - p0 * occf0 + __logf(1.0f + __expf(-a0))
                   + fmaxf(p1, 0.f) - p1 * occf1 + __logf(1.0f + __expf(-a1));
        float al = fabsf(pv0) + fabsf(pv1);
#pragma unroll
        for (int off = 1; off < 16; off <<= 1) {
            al   += __shfl_xor(al, off, 64);
            loss += __shfl_xor(loss, off, 64);
        }
        if (lane == 0) { wred[w][0] = al; wred[w][1] = loss; }
    }
    __syncthreads();
    if (tid == 0) {
        f32x2 s;
        s[0] = wred[0][0] + wred[1][0] + wred[2][0] + wred[3][0];
        s[1] = wred[0][1] + wred[1][1] + wred[2][1] + wred[3][1];
        *((f32x2*)(ws + PART_OFF) + blockIdx.x) = s;
    }
}

__global__ void __launch_bounds__(256)
interp_finalize(const char* __restrict__ ws, float* __restrict__ out)
{
    __shared__ float sal[4], sls[4];
    const int tid  = threadIdx.x;
    const int lane = tid & 63;
    const int w    = tid >> 6;
    float al = 0.0f, ls = 0.0f;
    const f32x2* part = (const f32x2*)(ws + PART_OFF);
    for (int i = tid; i < NBLK; i += 256) {
        f32x2 p = part[i];
        al += p[0]; ls += p[1];
    }
#pragma unroll
    for (int off = 1; off < 64; off <<= 1) {
        al += __shfl_xor(al, off, 64);
        ls += __shfl_xor(ls, off, 64);
    }
    if (lane == 0) { sal[w] = al; sls[w] = ls; }
    __syncthreads();
    if (tid == 0) {
        const float inv = 1.0f / (float)E_TOT;
        out[E_TOT]     = (sal[0] + sal[1] + sal[2] + sal[3]) * inv;
        out[E_TOT + 1] = (sls[0] + sls[1] + sls[2] + sls[3]) * inv;
    }
}

extern "C" void kernel_launch(void* const* d_in, const int* in_sizes, int n_in,
                              void* d_out, int out_size, void* d_ws, size_t ws_size,
                              hipStream_t stream) {
    (void)in_sizes; (void)n_in; (void)out_size;
    const float* pos_source = (const float*)d_in[0];
    const float* pos_target = (const float*)d_in[1];
    const float* latents    = (const float*)d_in[2];
    const float* varr       = (const float*)d_in[3];
    const float* drop_mask  = (const float*)d_in[4];
    const float* W_in       = (const float*)d_in[5];
    const float* b_in       = (const float*)d_in[6];
    const float* W1         = (const float*)d_in[7];
    const float* b1         = (const float*)d_in[8];
    const float* W2         = (const float*)d_in[9];
    const float* b2         = (const float*)d_in[10];
    const float* W_out      = (const float*)d_in[11];
    const float* b_out      = (const float*)d_in[12];
    const int*   row        = (const int*)d_in[13];
    const int*   col        = (const int*)d_in[14];
    const int*   occ        = (const int*)d_in[15];
    float* out = (float*)d_out;
    char*  ws  = (char*)d_ws;

    const bool packed = (ws_size >= (size_t)WS_NEED);
    prep<<<29, 256, 0, stream>>>(W_in, b_in, W1, b1, W2, b2, W_out, b_out, ws);
    if (packed) {
        prep_pack<<<2048, 256, 0, stream>>>(latents, varr, ws);
        interp_main<true><<<NBLK, 256, 0, stream>>>(
            pos_source, pos_target, latents, varr, drop_mask,
            row, col, occ, out, ws);
    } else {
        interp_main<false><<<NBLK, 256, 0, stream>>>(
            pos_source, pos_target, latents, varr, drop_mask,
            row, col, occ, out, ws);
    }
    interp_finalize<<<1, 256, 0, stream>>>(ws, out);
}

// Round 13
// 194.756 us; speedup vs baseline: 2.7647x; 2.7647x over previous
//
#include <hip/hip_runtime.h>
#include <math.h>

#define E_TOT 262144
#define N_SRC 16384
#define LDIM  128
#define MIN_VARF 0.001f
#define INV_SQRT2PIF 0.3989422804014327f
#define EPB   128            // edges per block (4 waves x 32)
#define NBLK  (E_TOT / EPB)  // 2048

typedef _Float16 half8  __attribute__((ext_vector_type(8)));
typedef __fp16   fp16x2 __attribute__((ext_vector_type(2)));
typedef float    f32x4  __attribute__((ext_vector_type(4)));
typedef float    f32x2  __attribute__((ext_vector_type(2)));
typedef unsigned int uint2v __attribute__((ext_vector_type(2)));

// ---- d_ws byte layout ----
#define BIAS_OFF  256        // 3 layers x 128 f32 (reordered [g*32+t*4+r])
#define WOUT_OFF  1792       // 2 x 128 f32
#define BOUT_OFF  2816       // 1 f32
#define PART_OFF  4096       // NBLK x f32x2 -> 16 KB
#define PK_L0     36864      // W_in  f16 frag-linear, 40960 B
#define PK_L1     77824      // W1    32768 B
#define PK_L2     110592     // W2    32768 B
#define PK_L0V    143360     // W_in^2 40960 B
#define PK_L1V    184320     // W1^2   32768 B
#define PK_L2V    217088     // W2^2   32768 B
#define LAT16_OFF 249856     // 4 MB
#define VAR16_OFF 4444160    // 4 MB
#define WS_NEED   8638464

__device__ __forceinline__ unsigned int pkrtz(float a, float b) {
    union { fp16x2 h; unsigned int u; } z;
    z.h = __builtin_amdgcn_cvt_pkrtz(a, b);
    return z.u;
}
__device__ __forceinline__ half8 to_h8(f32x4 a, f32x4 b) {
    union { half8 h; unsigned int u[4]; } z;
    z.u[0] = pkrtz(a[0], a[1]); z.u[1] = pkrtz(a[2], a[3]);
    z.u[2] = pkrtz(b[0], b[1]); z.u[3] = pkrtz(b[2], b[3]);
    return z.h;
}
__device__ __forceinline__ half8 ch_to_h8(uint2v lo, uint2v hi) {
    union { half8 h; unsigned int u[4]; } z;
    z.u[0] = lo[0]; z.u[1] = lo[1]; z.u[2] = hi[0]; z.u[3] = hi[1];
    return z.h;
}

// ADF-ReLU with A&S 7.1.26 erf sharing the pdf's exp(-r^2/2). 3 trans total.
__device__ __forceinline__ void adf_relu(float& m, float& v) {
    float vv = fmaxf(v, 1e-6f);
    float is = __builtin_amdgcn_rsqf(vv);    // 1/sd
    float sd = vv * is;
    float r  = m * is;
    float qq = 0.5f * r * r;
    float e  = __expf(-qq);
    float sp = sd * e * INV_SQRT2PIF;        // sd * pdf
    const float P = 0.23165247f;             // 0.3275911 / sqrt(2)
    float t  = __builtin_amdgcn_rcpf(fmaf(fabsf(r), P, 1.0f));
    float poly = t * fmaf(t, fmaf(t, fmaf(t, fmaf(t, 1.061405429f, -1.453152027f),
                                          1.421413741f), -0.284496736f), 0.254829592f);
    float erfa = fmaf(-poly, e, 1.0f);
    float cdf  = fmaf(copysignf(0.5f, r), erfa, 0.5f);
    float mo = fmaf(m, cdf, sp);
    float vo = fmaf(fmaf(m, m, vv), cdf, fmaf(m, sp, -mo * mo));
    m = mo; v = vo;
}

// Pack latents/var f32 -> f16 (RTE) into ws.
__global__ void prep_pack(const float* __restrict__ latents, const float* __restrict__ varr,
                          char* __restrict__ ws)
{
    int idx = blockIdx.x * 256 + threadIdx.x;          // [0, 524288)
    const int half = idx >> 18;
    const int j    = idx & 262143;
    const float* src = (half ? varr : latents) + (long)j * 8;
    char* dst = ws + (half ? VAR16_OFF : LAT16_OFF) + (long)j * 16;
    f32x4 a = *(const f32x4*)(src);
    f32x4 b = *(const f32x4*)(src + 4);
    half8 hv;
#pragma unroll
    for (int k = 0; k < 4; ++k) { hv[k] = (_Float16)a[k]; hv[k + 4] = (_Float16)b[k]; }
    *(half8*)dst = hv;
}

// Pack weights (W and W^2) fragment-linear f16.
// L0 (linear K): entry (ks,t,lane): A[16t+(lane&15)][32ks+8*(lane>>4)+j]
// L1/L2 (PERMUTED K so prev-layer acc registers ARE the B-frag):
//   pos = 32ks+8g+j  ->  k = 16*(2ks+(j>=4)) + 4g + (j&3)
__global__ void prep(const float* __restrict__ W_in, const float* __restrict__ b_in,
                     const float* __restrict__ W1,   const float* __restrict__ b1,
                     const float* __restrict__ W2,   const float* __restrict__ b2,
                     const float* __restrict__ W_out,const float* __restrict__ b_out,
                     char* __restrict__ ws)
{
    int idx = blockIdx.x * 256 + threadIdx.x;
    if (idx < 13312) {
        const float* W; long dstoff; int entry; bool lin; bool sq;
        if (idx < 5120) {
            sq = idx >= 2560; entry = idx - (sq ? 2560 : 0);
            W = W_in; dstoff = sq ? PK_L0V : PK_L0; lin = true;
        } else if (idx < 9216) {
            int j = idx - 5120; sq = j >= 2048; entry = j - (sq ? 2048 : 0);
            W = W1; dstoff = sq ? PK_L1V : PK_L1; lin = false;
        } else {
            int j = idx - 9216; sq = j >= 2048; entry = j - (sq ? 2048 : 0);
            W = W2; dstoff = sq ? PK_L2V : PK_L2; lin = false;
        }
        int ks   = entry >> 9;
        int rest = entry & 511;
        int t    = rest >> 6;
        int lane = rest & 63;
        int rowi = t * 16 + (lane & 15);
        int gp   = lane >> 4;
        half8 hv;
#pragma unroll
        for (int j = 0; j < 8; ++j) {
            int k;
            float v;
            if (lin) {
                k = ks * 32 + gp * 8 + j;
                v = (k < 131) ? W[rowi * 131 + k] : 0.0f;
            } else {
                k = (2 * ks + (j >= 4 ? 1 : 0)) * 16 + 4 * gp + (j & 3);
                v = W[rowi * 128 + k];
            }
            if (sq) v = v * v;
            hv[j] = (_Float16)v;
        }
        *(half8*)(ws + dstoff + (long)entry * 16) = hv;
    } else if (idx < 13312 + 384) {
        int j = idx - 13312; int layer = j >> 7; int pidx = j & 127;
        int gg = pidx >> 5, t = (pidx >> 2) & 7, r = pidx & 3;
        int n = t * 16 + gg * 4 + r;
        const float* b = layer == 0 ? b_in : (layer == 1 ? b1 : b2);
        ((float*)(ws + BIAS_OFF))[layer * 128 + pidx] = b[n];
    } else if (idx < 13312 + 384 + 256) {
        int j = idx - 13312 - 384; int path = j >> 7; int pidx = j & 127;
        int gg = pidx >> 5, t = (pidx >> 2) & 7, r = pidx & 3;
        int n = t * 16 + gg * 4 + r;
        float v = W_out[n];
        if (path) v = v * v;
        ((float*)(ws + WOUT_OFF))[path * 128 + pidx] = v;
    } else if (idx == 13312 + 384 + 256) {
        ((float*)(ws + BOUT_OFF))[0] = b_out[0];
    }
}

// epilogue: bias + ADF-ReLU, pack f16 chunks (registers, no LDS)
__device__ __forceinline__ void epi_reg(const f32x4* am, const f32x4* av, const f32x4* bp,
                                        uint2v* chm, uint2v* chv)
{
#pragma unroll
    for (int t = 0; t < 8; ++t) {
        f32x4 b4 = bp[t];
        float m0 = am[t][0] + b4[0], m1 = am[t][1] + b4[1];
        float m2 = am[t][2] + b4[2], m3 = am[t][3] + b4[3];
        float v0 = av[t][0], v1 = av[t][1], v2 = av[t][2], v3 = av[t][3];
        adf_relu(m0, v0); adf_relu(m1, v1); adf_relu(m2, v2); adf_relu(m3, v3);
        uint2v sm = {pkrtz(m0, m1), pkrtz(m2, m3)};
        uint2v sv = {pkrtz(v0, v1), pkrtz(v2, v3)};
        chm[t] = sm; chv[t] = sv;
    }
}

template <bool PACKED>
__global__ void __launch_bounds__(256, 2)
interp_main(const float* __restrict__ pos_source, const float* __restrict__ pos_target,
            const float* __restrict__ latents,    const float* __restrict__ varr,
            const float* __restrict__ drop_mask,
            const int* __restrict__ row, const int* __restrict__ col, const int* __restrict__ occ,
            float* __restrict__ out, char* __restrict__ ws)
{
    __shared__ float wred[4][2];

    const int tid  = threadIdx.x;
    const int lane = tid & 63;
    const int w    = tid >> 6;
    const int q    = lane & 15;
    const int g    = lane >> 4;
    const int g8   = g * 8;
    const int er0  = w * 32 + q;
    const int er1  = er0 + 16;
    const int ge0  = blockIdx.x * EPB + er0;
    const int ge1  = ge0 + 16;

    const int c0 = col[ge0], c1 = col[ge1];
    const int r0 = row[ge0], r1 = row[ge1];
    const float occf0 = (float)occ[r0];
    const float occf1 = (float)occ[r1];
    const float px0 = pos_target[r0 * 3 + 0] - pos_source[c0 * 3 + 0];
    const float py0 = pos_target[r0 * 3 + 1] - pos_source[c0 * 3 + 1];
    const float pz0 = pos_target[r0 * 3 + 2] - pos_source[c0 * 3 + 2];
    const float px1 = pos_target[r1 * 3 + 0] - pos_source[c1 * 3 + 0];
    const float py1 = pos_target[r1 * 3 + 1] - pos_source[c1 * 3 + 1];
    const float pz1 = pos_target[r1 * 3 + 2] - pos_source[c1 * 3 + 2];

    f32x4 acm0[8], acv0[8], acm1[8], acv1[8];
    const f32x4 zz = {0.0f, 0.0f, 0.0f, 0.0f};
#pragma unroll
    for (int t = 0; t < 8; ++t) { acm0[t] = zz; acv0[t] = zz; acm1[t] = zz; acv1[t] = zz; }

    uint2v chm0[8], chv0[8], chm1[8], chv1[8];

    // ================= layer 0: B from packed f16 latents, A/A^2 from L2 =====
    {
        const char* pkm = ws + PK_L0  + lane * 16;
        const char* pkv = ws + PK_L0V + lane * 16;
#pragma unroll
        for (int ks = 0; ks < 4; ++ks) {
            half8 bm0, bv0, bm1, bv1;
            if (PACKED) {
                const long o0 = (long)c0 * 256 + ks * 64 + g8 * 2;
                const long o1 = (long)c1 * 256 + ks * 64 + g8 * 2;
                bm0 = *(const half8*)(ws + LAT16_OFF + o0);
                bv0 = *(const half8*)(ws + VAR16_OFF + o0);
                bm1 = *(const half8*)(ws + LAT16_OFF + o1);
                bv1 = *(const half8*)(ws + VAR16_OFF + o1);
            } else {
                const f32x4* a0 = (const f32x4*)(latents + (long)c0 * LDIM + ks * 32 + g8);
                const f32x4* s0 = (const f32x4*)(varr    + (long)c0 * LDIM + ks * 32 + g8);
                const f32x4* a1 = (const f32x4*)(latents + (long)c1 * LDIM + ks * 32 + g8);
                const f32x4* s1 = (const f32x4*)(varr    + (long)c1 * LDIM + ks * 32 + g8);
                bm0 = to_h8(a0[0], a0[1]); bv0 = to_h8(s0[0], s0[1]);
                bm1 = to_h8(a1[0], a1[1]); bv1 = to_h8(s1[0], s1[1]);
            }
            const char* pmk = pkm + ks * 8192;
            const char* pvk = pkv + ks * 8192;
#pragma unroll
            for (int t = 0; t < 8; ++t) {
                half8 am = *(const half8*)(pmk + t * 1024);
                half8 av = *(const half8*)(pvk + t * 1024);
                acm0[t] = __builtin_amdgcn_mfma_f32_16x16x32_f16(am, bm0, acm0[t], 0, 0, 0);
                acm1[t] = __builtin_amdgcn_mfma_f32_16x16x32_f16(am, bm1, acm1[t], 0, 0, 0);
                acv0[t] = __builtin_amdgcn_mfma_f32_16x16x32_f16(av, bv0, acv0[t], 0, 0, 0);
                acv1[t] = __builtin_amdgcn_mfma_f32_16x16x32_f16(av, bv1, acv1[t], 0, 0, 0);
            }
        }
        // ks = 4: pos_rel (k = 128..130)
        half8 bp0 = {(_Float16)0.f, (_Float16)0.f, (_Float16)0.f, (_Float16)0.f,
                     (_Float16)0.f, (_Float16)0.f, (_Float16)0.f, (_Float16)0.f};
        half8 bp1 = bp0;
        if (g == 0) {
            bp0[0] = (_Float16)px0; bp0[1] = (_Float16)py0; bp0[2] = (_Float16)pz0;
            bp1[0] = (_Float16)px1; bp1[1] = (_Float16)py1; bp1[2] = (_Float16)pz1;
        }
        const char* pmk = pkm + 4 * 8192;
        const char* pvk = pkv + 4 * 8192;
#pragma unroll
        for (int t = 0; t < 8; ++t) {
            half8 am = *(const half8*)(pmk + t * 1024);
            half8 av = *(const half8*)(pvk + t * 1024);
            acm0[t] = __builtin_amdgcn_mfma_f32_16x16x32_f16(am, bp0, acm0[t], 0, 0, 0);
            acm1[t] = __builtin_amdgcn_mfma_f32_16x16x32_f16(am, bp1, acm1[t], 0, 0, 0);
            acv0[t] = __builtin_amdgcn_mfma_f32_16x16x32_f16(av, bp0, acv0[t], 0, 0, 0);
            acv1[t] = __builtin_amdgcn_mfma_f32_16x16x32_f16(av, bp1, acv1[t], 0, 0, 0);
        }
        const f32x4* bp = (const f32x4*)(ws + BIAS_OFF) + g8;
        epi_reg(acm0, acv0, bp, chm0, chv0);
        epi_reg(acm1, acv1, bp, chm1, chv1);
    }

    // ================= layers 1,2: B from prev acc registers (permuted W/W^2) ====
#pragma unroll
    for (int layer = 1; layer < 3; ++layer) {
        const char* pkm = ws + (layer == 1 ? PK_L1  : PK_L2)  + lane * 16;
        const char* pkv = ws + (layer == 1 ? PK_L1V : PK_L2V) + lane * 16;
#pragma unroll
        for (int t = 0; t < 8; ++t) { acm0[t] = zz; acv0[t] = zz; acm1[t] = zz; acv1[t] = zz; }
#pragma unroll
        for (int ks = 0; ks < 4; ++ks) {
            half8 bm0 = ch_to_h8(chm0[2 * ks], chm0[2 * ks + 1]);
            half8 bv0 = ch_to_h8(chv0[2 * ks], chv0[2 * ks + 1]);
            half8 bm1 = ch_to_h8(chm1[2 * ks], chm1[2 * ks + 1]);
            half8 bv1 = ch_to_h8(chv1[2 * ks], chv1[2 * ks + 1]);
            const char* pmk = pkm + ks * 8192;
            const char* pvk = pkv + ks * 8192;
#pragma unroll
            for (int t = 0; t < 8; ++t) {
                half8 am = *(const half8*)(pmk + t * 1024);
                half8 av = *(const half8*)(pvk + t * 1024);
                acm0[t] = __builtin_amdgcn_mfma_f32_16x16x32_f16(am, bm0, acm0[t], 0, 0, 0);
                acm1[t] = __builtin_amdgcn_mfma_f32_16x16x32_f16(am, bm1, acm1[t], 0, 0, 0);
                acv0[t] = __builtin_amdgcn_mfma_f32_16x16x32_f16(av, bv0, acv0[t], 0, 0, 0);
                acv1[t] = __builtin_amdgcn_mfma_f32_16x16x32_f16(av, bv1, acv1[t], 0, 0, 0);
            }
        }
        if (layer == 1) {
            const f32x4* bp = (const f32x4*)(ws + BIAS_OFF) + 32 + g8;
            epi_reg(acm0, acv0, bp, chm0, chv0);
            epi_reg(acm1, acv1, bp, chm1, chv1);
        }
    }

    // ================= final epilogue: dropout + W_out dot + reductions =================
    {
        const f32x4* wmp = (const f32x4*)(ws + WOUT_OFF);
        const f32x4* bp  = (const f32x4*)(ws + BIAS_OFF) + 64 + g8;
        const f32x4* dm0 = (const f32x4*)(drop_mask + (size_t)ge0 * LDIM) + g;
        const f32x4* dm1 = (const f32x4*)(drop_mask + (size_t)ge1 * LDIM) + g;
        float pm0 = 0.f, pv0 = 0.f, pm1 = 0.f, pv1 = 0.f;
#pragma unroll
        for (int t = 0; t < 8; ++t) {
            f32x4 b4 = bp[t];
            f32x4 w4 = wmp[g8 + t];
            f32x4 s4 = wmp[32 + g8 + t];
            f32x4 d0 = __builtin_nontemporal_load(dm0 + t * 4);
            f32x4 d1 = __builtin_nontemporal_load(dm1 + t * 4);
#pragma unroll
            for (int j = 0; j < 4; ++j) {
                float m0 = (acm0[t][j] + b4[j]) * d0[j];
                float v0 = acv0[t][j] * d0[j] * d0[j] + MIN_VARF;
                float m1 = (acm1[t][j] + b4[j]) * d1[j];
                float v1 = acv1[t][j] * d1[j] * d1[j] + MIN_VARF;
                pm0 = fmaf(w4[j], m0, pm0); pv0 = fmaf(s4[j], v0, pv0);
                pm1 = fmaf(w4[j], m1, pm1); pv1 = fmaf(s4[j], v1, pv1);
            }
        }
        pm0 += __shfl_xor(pm0, 16, 64); pm0 += __shfl_xor(pm0, 32, 64);
        pv0 += __shfl_xor(pv0, 16, 64); pv0 += __shfl_xor(pv0, 32, 64);
        pm1 += __shfl_xor(pm1, 16, 64); pm1 += __shfl_xor(pm1, 32, 64);
        pv1 += __shfl_xor(pv1, 16, 64); pv1 += __shfl_xor(pv1, 32, 64);
        float bout = *(const float*)(ws + BOUT_OFF);
        float p0 = pm0 + bout;
        float p1 = pm1 + bout;
        if (lane < 16) {
            out[ge0] = p0;            out[ge1] = p1;
            out[E_TOT + 2 + ge0] = occf0;
            out[E_TOT + 2 + ge1] = occf1;
        }
        float a0 = fabsf(p0), a1 = fabsf(p1);
        float loss = fmaxf(p0, 0.f) - p0 * occf0 + __logf(1.0f + __expf(-a0))
                   + fmaxf(p1, 0.f) - p1 * occf1 + __logf(1.0f + __expf(-a1));
        float al = fabsf(pv0) + fabsf(pv1);
#pragma unroll
        for (int off = 1; off < 16; off <<= 1) {
            al   += __shfl_xor(al, off, 64);
            loss += __shfl_xor(loss, off, 64);
        }
        if (lane == 0) { wred[w][0] = al; wred[w][1] = loss; }
    }
    __syncthreads();
    if (tid == 0) {
        f32x2 s;
        s[0] = wred[0][0] + wred[1][0] + wred[2][0] + wred[3][0];
        s[1] = wred[0][1] + wred[1][1] + wred[2][1] + wred[3][1];
        *((f32x2*)(ws + PART_OFF) + blockIdx.x) = s;
    }
}

__global__ void __launch_bounds__(256)
interp_finalize(const char* __restrict__ ws, float* __restrict__ out)
{
    __shared__ float sal[4], sls[4];
    const int tid  = threadIdx.x;
    const int lane = tid & 63;
    const int w    = tid >> 6;
    float al = 0.0f, ls = 0.0f;
    const f32x2* part = (const f32x2*)(ws + PART_OFF);
    for (int i = tid; i < NBLK; i += 256) {
        f32x2 p = part[i];
        al += p[0]; ls += p[1];
    }
#pragma unroll
    for (int off = 1; off < 64; off <<= 1) {
        al += __shfl_xor(al, off, 64);
        ls += __shfl_xor(ls, off, 64);
    }
    if (lane == 0) { sal[w] = al; sls[w] = ls; }
    __syncthreads();
    if (tid == 0) {
        const float inv = 1.0f / (float)E_TOT;
        out[E_TOT]     = (sal[0] + sal[1] + sal[2] + sal[3]) * inv;
        out[E_TOT + 1] = (sls[0] + sls[1] + sls[2] + sls[3]) * inv;
    }
}

extern "C" void kernel_launch(void* const* d_in, const int* in_sizes, int n_in,
                              void* d_out, int out_size, void* d_ws, size_t ws_size,
                              hipStream_t stream) {
    (void)in_sizes; (void)n_in; (void)out_size;
    const float* pos_source = (const float*)d_in[0];
    const float* pos_target = (const float*)d_in[1];
    const float* latents    = (const float*)d_in[2];
    const float* varr       = (const float*)d_in[3];
    const float* drop_mask  = (const float*)d_in[4];
    const float* W_in       = (const float*)d_in[5];
    const float* b_in       = (const float*)d_in[6];
    const float* W1         = (const float*)d_in[7];
    const float* b1         = (const float*)d_in[8];
    const float* W2         = (const float*)d_in[9];
    const float* b2         = (const float*)d_in[10];
    const float* W_out      = (const float*)d_in[11];
    const float* b_out      = (const float*)d_in[12];
    const int*   row        = (const int*)d_in[13];
    const int*   col        = (const int*)d_in[14];
    const int*   occ        = (const int*)d_in[15];
    float* out = (float*)d_out;
    char*  ws  = (char*)d_ws;

    const bool packed = (ws_size >= (size_t)WS_NEED);
    prep<<<55, 256, 0, stream>>>(W_in, b_in, W1, b1, W2, b2, W_out, b_out, ws);
    if (packed) {
        prep_pack<<<2048, 256, 0, stream>>>(latents, varr, ws);
        interp_main<true><<<NBLK, 256, 0, stream>>>(
            pos_source, pos_target, latents, varr, drop_mask,
            row, col, occ, out, ws);
    } else {
        interp_main<false><<<NBLK, 256, 0, stream>>>(
            pos_source, pos_target, latents, varr, drop_mask,
            row, col, occ, out, ws);
    }
    interp_finalize<<<1, 256, 0, stream>>>(ws, out);
}

// Round 14
// 142.778 us; speedup vs baseline: 3.7711x; 1.3640x over previous
//
#include <hip/hip_runtime.h>
#include <math.h>

#define E_TOT 262144
#define N_SRC 16384
#define LDIM  128
#define MIN_VARF 0.001f
#define INV_SQRT2PIF 0.3989422804014327f
#define EPB   128            // edges per block (4 waves x 32)
#define NBLK  (E_TOT / EPB)  // 2048

typedef _Float16 half8  __attribute__((ext_vector_type(8)));
typedef __fp16   fp16x2 __attribute__((ext_vector_type(2)));
typedef float    f32x4  __attribute__((ext_vector_type(4)));
typedef float    f32x2  __attribute__((ext_vector_type(2)));
typedef unsigned int uint2v __attribute__((ext_vector_type(2)));

// ---- d_ws byte layout ----
#define BIAS_OFF  256        // 3 layers x 128 f32 (reordered [g*32+t*4+r])
#define WOUT_OFF  1792       // 2 x 128 f32
#define BOUT_OFF  2816       // 1 f32
#define PART_OFF  4096       // NBLK x f32x2 -> 16 KB
#define PK_L0     36864      // W_in  f16 frag-linear, 40960 B
#define PK_L1     77824      // W1    32768 B
#define PK_L2     110592     // W2    32768 B
#define LAT16_OFF 143360     // 4 MB
#define VAR16_OFF 4337664    // 4 MB
#define WS_NEED   8531968

__device__ __forceinline__ unsigned int pkrtz(float a, float b) {
    union { fp16x2 h; unsigned int u; } z;
    z.h = __builtin_amdgcn_cvt_pkrtz(a, b);
    return z.u;
}
__device__ __forceinline__ half8 to_h8(f32x4 a, f32x4 b) {
    union { half8 h; unsigned int u[4]; } z;
    z.u[0] = pkrtz(a[0], a[1]); z.u[1] = pkrtz(a[2], a[3]);
    z.u[2] = pkrtz(b[0], b[1]); z.u[3] = pkrtz(b[2], b[3]);
    return z.h;
}
__device__ __forceinline__ half8 ch_to_h8(uint2v lo, uint2v hi) {
    union { half8 h; unsigned int u[4]; } z;
    z.u[0] = lo[0]; z.u[1] = lo[1]; z.u[2] = hi[0]; z.u[3] = hi[1];
    return z.h;
}

// ADF-ReLU with A&S 7.1.26 erf sharing the pdf's exp(-r^2/2). 3 trans total.
__device__ __forceinline__ void adf_relu(float& m, float& v) {
    float vv = fmaxf(v, 1e-6f);
    float is = __builtin_amdgcn_rsqf(vv);    // 1/sd
    float sd = vv * is;
    float r  = m * is;
    float qq = 0.5f * r * r;
    float e  = __expf(-qq);
    float sp = sd * e * INV_SQRT2PIF;        // sd * pdf
    const float P = 0.23165247f;             // 0.3275911 / sqrt(2)
    float t  = __builtin_amdgcn_rcpf(fmaf(fabsf(r), P, 1.0f));
    float poly = t * fmaf(t, fmaf(t, fmaf(t, fmaf(t, 1.061405429f, -1.453152027f),
                                          1.421413741f), -0.284496736f), 0.254829592f);
    float erfa = fmaf(-poly, e, 1.0f);
    float cdf  = fmaf(copysignf(0.5f, r), erfa, 0.5f);
    float mo = fmaf(m, cdf, sp);
    float vo = fmaf(fmaf(m, m, vv), cdf, fmaf(m, sp, -mo * mo));
    m = mo; v = vo;
}

// Pack latents/var f32 -> f16 (RTE) into ws.
__global__ void prep_pack(const float* __restrict__ latents, const float* __restrict__ varr,
                          char* __restrict__ ws)
{
    int idx = blockIdx.x * 256 + threadIdx.x;          // [0, 524288)
    const int half = idx >> 18;
    const int j    = idx & 262143;
    const float* src = (half ? varr : latents) + (long)j * 8;
    char* dst = ws + (half ? VAR16_OFF : LAT16_OFF) + (long)j * 16;
    f32x4 a = *(const f32x4*)(src);
    f32x4 b = *(const f32x4*)(src + 4);
    half8 hv;
#pragma unroll
    for (int k = 0; k < 4; ++k) { hv[k] = (_Float16)a[k]; hv[k + 4] = (_Float16)b[k]; }
    *(half8*)dst = hv;
}

// Pack weights fragment-linear f16.
// L0 (linear K): entry (ks,t,lane): A[16t+(lane&15)][32ks+8*(lane>>4)+j]
// L1/L2 (PERMUTED K so prev-layer acc registers ARE the B-frag):
//   pos = 32ks+8g+j  ->  k = 16*(2ks+(j>=4)) + 4g + (j&3)
__global__ void prep(const float* __restrict__ W_in, const float* __restrict__ b_in,
                     const float* __restrict__ W1,   const float* __restrict__ b1,
                     const float* __restrict__ W2,   const float* __restrict__ b2,
                     const float* __restrict__ W_out,const float* __restrict__ b_out,
                     char* __restrict__ ws)
{
    int idx = blockIdx.x * 256 + threadIdx.x;
    if (idx < 6656) {
        const float* W; long dstoff; int entry; bool lin;
        if (idx < 2560)      { entry = idx;        W = W_in; dstoff = PK_L0; lin = true;  }
        else if (idx < 4608) { entry = idx - 2560; W = W1;   dstoff = PK_L1; lin = false; }
        else                 { entry = idx - 4608; W = W2;   dstoff = PK_L2; lin = false; }
        int ks   = entry >> 9;
        int rest = entry & 511;
        int t    = rest >> 6;
        int lane = rest & 63;
        int rowi = t * 16 + (lane & 15);
        int gp   = lane >> 4;
        half8 hv;
        if (lin) {
            int k0 = ks * 32 + gp * 8;
#pragma unroll
            for (int j = 0; j < 8; ++j) {
                int k = k0 + j;
                hv[j] = (_Float16)((k < 131) ? W[rowi * 131 + k] : 0.0f);
            }
        } else {
#pragma unroll
            for (int j = 0; j < 8; ++j) {
                int k = (2 * ks + (j >= 4 ? 1 : 0)) * 16 + 4 * gp + (j & 3);
                hv[j] = (_Float16)W[rowi * 128 + k];
            }
        }
        *(half8*)(ws + dstoff + (long)entry * 16) = hv;
    } else if (idx < 6656 + 384) {
        int j = idx - 6656; int layer = j >> 7; int pidx = j & 127;
        int gg = pidx >> 5, t = (pidx >> 2) & 7, r = pidx & 3;
        int n = t * 16 + gg * 4 + r;
        const float* b = layer == 0 ? b_in : (layer == 1 ? b1 : b2);
        ((float*)(ws + BIAS_OFF))[layer * 128 + pidx] = b[n];
    } else if (idx < 6656 + 384 + 256) {
        int j = idx - 6656 - 384; int path = j >> 7; int pidx = j & 127;
        int gg = pidx >> 5, t = (pidx >> 2) & 7, r = pidx & 3;
        int n = t * 16 + gg * 4 + r;
        float v = W_out[n];
        if (path) v = v * v;
        ((float*)(ws + WOUT_OFF))[path * 128 + pidx] = v;
    } else if (idx == 6656 + 384 + 256) {
        ((float*)(ws + BOUT_OFF))[0] = b_out[0];
    }
}

// epilogue: bias + ADF-ReLU, pack f16 chunks (registers, no LDS)
__device__ __forceinline__ void epi_reg(const f32x4* am, const f32x4* av, const f32x4* bp,
                                        uint2v* chm, uint2v* chv)
{
#pragma unroll
    for (int t = 0; t < 8; ++t) {
        f32x4 b4 = bp[t];
        float m0 = am[t][0] + b4[0], m1 = am[t][1] + b4[1];
        float m2 = am[t][2] + b4[2], m3 = am[t][3] + b4[3];
        float v0 = av[t][0], v1 = av[t][1], v2 = av[t][2], v3 = av[t][3];
        adf_relu(m0, v0); adf_relu(m1, v1); adf_relu(m2, v2); adf_relu(m3, v3);
        uint2v sm = {pkrtz(m0, m1), pkrtz(m2, m3)};
        uint2v sv = {pkrtz(v0, v1), pkrtz(v2, v3)};
        chm[t] = sm; chv[t] = sv;
    }
}

template <bool PACKED>
__global__ void __launch_bounds__(256, 2)
interp_main(const float* __restrict__ pos_source, const float* __restrict__ pos_target,
            const float* __restrict__ latents,    const float* __restrict__ varr,
            const float* __restrict__ drop_mask,
            const int* __restrict__ row, const int* __restrict__ col, const int* __restrict__ occ,
            float* __restrict__ out, char* __restrict__ ws)
{
    __shared__ float wred[4][2];

    const int tid  = threadIdx.x;
    const int lane = tid & 63;
    const int w    = tid >> 6;
    const int q    = lane & 15;
    const int g    = lane >> 4;
    const int g8   = g * 8;
    const int er0  = w * 32 + q;
    const int er1  = er0 + 16;
    const int ge0  = blockIdx.x * EPB + er0;
    const int ge1  = ge0 + 16;

    const int c0 = col[ge0], c1 = col[ge1];
    const int r0 = row[ge0], r1 = row[ge1];
    const float occf0 = (float)occ[r0];
    const float occf1 = (float)occ[r1];
    const float px0 = pos_target[r0 * 3 + 0] - pos_source[c0 * 3 + 0];
    const float py0 = pos_target[r0 * 3 + 1] - pos_source[c0 * 3 + 1];
    const float pz0 = pos_target[r0 * 3 + 2] - pos_source[c0 * 3 + 2];
    const float px1 = pos_target[r1 * 3 + 0] - pos_source[c1 * 3 + 0];
    const float py1 = pos_target[r1 * 3 + 1] - pos_source[c1 * 3 + 1];
    const float pz1 = pos_target[r1 * 3 + 2] - pos_source[c1 * 3 + 2];

    f32x4 acm0[8], acv0[8], acm1[8], acv1[8];
    const f32x4 zz = {0.0f, 0.0f, 0.0f, 0.0f};
#pragma unroll
    for (int t = 0; t < 8; ++t) { acm0[t] = zz; acv0[t] = zz; acm1[t] = zz; acv1[t] = zz; }

    uint2v chm0[8], chv0[8], chm1[8], chv1[8];

    // ================= layer 0: B from packed f16 latents, A shared across 2 edges =====
    {
        const char* pk = ws + PK_L0 + lane * 16;
#pragma unroll
        for (int ks = 0; ks < 4; ++ks) {
            half8 bm0, bv0, bm1, bv1;
            if (PACKED) {
                const long o0 = (long)c0 * 256 + ks * 64 + g8 * 2;
                const long o1 = (long)c1 * 256 + ks * 64 + g8 * 2;
                bm0 = *(const half8*)(ws + LAT16_OFF + o0);
                bv0 = *(const half8*)(ws + VAR16_OFF + o0);
                bm1 = *(const half8*)(ws + LAT16_OFF + o1);
                bv1 = *(const half8*)(ws + VAR16_OFF + o1);
            } else {
                const f32x4* a0 = (const f32x4*)(latents + (long)c0 * LDIM + ks * 32 + g8);
                const f32x4* s0 = (const f32x4*)(varr    + (long)c0 * LDIM + ks * 32 + g8);
                const f32x4* a1 = (const f32x4*)(latents + (long)c1 * LDIM + ks * 32 + g8);
                const f32x4* s1 = (const f32x4*)(varr    + (long)c1 * LDIM + ks * 32 + g8);
                bm0 = to_h8(a0[0], a0[1]); bv0 = to_h8(s0[0], s0[1]);
                bm1 = to_h8(a1[0], a1[1]); bv1 = to_h8(s1[0], s1[1]);
            }
            const char* pmk = pk + ks * 8192;
            __builtin_amdgcn_s_setprio(1);
#pragma unroll
            for (int t = 0; t < 8; ++t) {
                half8 am = *(const half8*)(pmk + t * 1024);
                half8 av = am * am;
                acm0[t] = __builtin_amdgcn_mfma_f32_16x16x32_f16(am, bm0, acm0[t], 0, 0, 0);
                acm1[t] = __builtin_amdgcn_mfma_f32_16x16x32_f16(am, bm1, acm1[t], 0, 0, 0);
                acv0[t] = __builtin_amdgcn_mfma_f32_16x16x32_f16(av, bv0, acv0[t], 0, 0, 0);
                acv1[t] = __builtin_amdgcn_mfma_f32_16x16x32_f16(av, bv1, acv1[t], 0, 0, 0);
            }
            __builtin_amdgcn_s_setprio(0);
        }
        // ks = 4: pos_rel (k = 128..130)
        half8 bp0 = {(_Float16)0.f, (_Float16)0.f, (_Float16)0.f, (_Float16)0.f,
                     (_Float16)0.f, (_Float16)0.f, (_Float16)0.f, (_Float16)0.f};
        half8 bp1 = bp0;
        if (g == 0) {
            bp0[0] = (_Float16)px0; bp0[1] = (_Float16)py0; bp0[2] = (_Float16)pz0;
            bp1[0] = (_Float16)px1; bp1[1] = (_Float16)py1; bp1[2] = (_Float16)pz1;
        }
        const char* pmk = pk + 4 * 8192;
        __builtin_amdgcn_s_setprio(1);
#pragma unroll
        for (int t = 0; t < 8; ++t) {
            half8 am = *(const half8*)(pmk + t * 1024);
            half8 av = am * am;
            acm0[t] = __builtin_amdgcn_mfma_f32_16x16x32_f16(am, bp0, acm0[t], 0, 0, 0);
            acm1[t] = __builtin_amdgcn_mfma_f32_16x16x32_f16(am, bp1, acm1[t], 0, 0, 0);
            acv0[t] = __builtin_amdgcn_mfma_f32_16x16x32_f16(av, bp0, acv0[t], 0, 0, 0);
            acv1[t] = __builtin_amdgcn_mfma_f32_16x16x32_f16(av, bp1, acv1[t], 0, 0, 0);
        }
        __builtin_amdgcn_s_setprio(0);
        const f32x4* bp = (const f32x4*)(ws + BIAS_OFF) + g8;
        epi_reg(acm0, acv0, bp, chm0, chv0);
        epi_reg(acm1, acv1, bp, chm1, chv1);
    }

    // ================= layers 1,2: B from prev acc registers (permuted W), A shared ====
#pragma unroll
    for (int layer = 1; layer < 3; ++layer) {
        const char* pk = ws + (layer == 1 ? PK_L1 : PK_L2) + lane * 16;
#pragma unroll
        for (int t = 0; t < 8; ++t) { acm0[t] = zz; acv0[t] = zz; acm1[t] = zz; acv1[t] = zz; }
#pragma unroll
        for (int ks = 0; ks < 4; ++ks) {
            half8 bm0 = ch_to_h8(chm0[2 * ks], chm0[2 * ks + 1]);
            half8 bv0 = ch_to_h8(chv0[2 * ks], chv0[2 * ks + 1]);
            half8 bm1 = ch_to_h8(chm1[2 * ks], chm1[2 * ks + 1]);
            half8 bv1 = ch_to_h8(chv1[2 * ks], chv1[2 * ks + 1]);
            const char* pmk = pk + ks * 8192;
            __builtin_amdgcn_s_setprio(1);
#pragma unroll
            for (int t = 0; t < 8; ++t) {
                half8 am = *(const half8*)(pmk + t * 1024);
                half8 av = am * am;
                acm0[t] = __builtin_amdgcn_mfma_f32_16x16x32_f16(am, bm0, acm0[t], 0, 0, 0);
                acm1[t] = __builtin_amdgcn_mfma_f32_16x16x32_f16(am, bm1, acm1[t], 0, 0, 0);
                acv0[t] = __builtin_amdgcn_mfma_f32_16x16x32_f16(av, bv0, acv0[t], 0, 0, 0);
                acv1[t] = __builtin_amdgcn_mfma_f32_16x16x32_f16(av, bv1, acv1[t], 0, 0, 0);
            }
            __builtin_amdgcn_s_setprio(0);
        }
        if (layer == 1) {
            const f32x4* bp = (const f32x4*)(ws + BIAS_OFF) + 32 + g8;
            epi_reg(acm0, acv0, bp, chm0, chv0);
            epi_reg(acm1, acv1, bp, chm1, chv1);
        }
    }

    // ================= final epilogue: dropout + W_out dot + reductions =================
    {
        const f32x4* wmp = (const f32x4*)(ws + WOUT_OFF);
        const f32x4* bp  = (const f32x4*)(ws + BIAS_OFF) + 64 + g8;
        const f32x4* dm0 = (const f32x4*)(drop_mask + (size_t)ge0 * LDIM) + g;
        const f32x4* dm1 = (const f32x4*)(drop_mask + (size_t)ge1 * LDIM) + g;
        float pm0 = 0.f, pv0 = 0.f, pm1 = 0.f, pv1 = 0.f;
#pragma unroll
        for (int t = 0; t < 8; ++t) {
            f32x4 b4 = bp[t];
            f32x4 w4 = wmp[g8 + t];
            f32x4 s4 = wmp[32 + g8 + t];
            f32x4 d0 = __builtin_nontemporal_load(dm0 + t * 4);
            f32x4 d1 = __builtin_nontemporal_load(dm1 + t * 4);
#pragma unroll
            for (int j = 0; j < 4; ++j) {
                float m0 = (acm0[t][j] + b4[j]) * d0[j];
                float v0 = acv0[t][j] * d0[j] * d0[j] + MIN_VARF;
                float m1 = (acm1[t][j] + b4[j]) * d1[j];
                float v1 = acv1[t][j] * d1[j] * d1[j] + MIN_VARF;
                pm0 = fmaf(w4[j], m0, pm0); pv0 = fmaf(s4[j], v0, pv0);
                pm1 = fmaf(w4[j], m1, pm1); pv1 = fmaf(s4[j], v1, pv1);
            }
        }
        pm0 += __shfl_xor(pm0, 16, 64); pm0 += __shfl_xor(pm0, 32, 64);
        pv0 += __shfl_xor(pv0, 16, 64); pv0 += __shfl_xor(pv0, 32, 64);
        pm1 += __shfl_xor(pm1, 16, 64); pm1 += __shfl_xor(pm1, 32, 64);
        pv1 += __shfl_xor(pv1, 16, 64); pv1 += __shfl_xor(pv1, 32, 64);
        float bout = *(const float*)(ws + BOUT_OFF);
        float p0 = pm0 + bout;
        float p1 = pm1 + bout;
        if (lane < 16) {
            out[ge0] = p0;            out[ge1] = p1;
            out[E_TOT + 2 + ge0] = occf0;
            out[E_TOT + 2 + ge1] = occf1;
        }
        float a0 = fabsf(p0), a1 = fabsf(p1);
        float loss = fmaxf(p0, 0.f) - p0 * occf0 + __logf(1.0f + __expf(-a0))
                   + fmaxf(p1, 0.f) - p1 * occf1 + __logf(1.0f + __expf(-a1));
        float al = fabsf(pv0) + fabsf(pv1);
#pragma unroll
        for (int off = 1; off < 16; off <<= 1) {
            al   += __shfl_xor(al, off, 64);
            loss += __shfl_xor(loss, off, 64);
        }
        if (lane == 0) { wred[w][0] = al; wred[w][1] = loss; }
    }
    __syncthreads();
    if (tid == 0) {
        f32x2 s;
        s[0] = wred[0][0] + wred[1][0] + wred[2][0] + wred[3][0];
        s[1] = wred[0][1] + wred[1][1] + wred[2][1] + wred[3][1];
        *((f32x2*)(ws + PART_OFF) + blockIdx.x) = s;
    }
}

__global__ void __launch_bounds__(256)
interp_finalize(const char* __restrict__ ws, float* __restrict__ out)
{
    __shared__ float sal[4], sls[4];
    const int tid  = threadIdx.x;
    const int lane = tid & 63;
    const int w    = tid >> 6;
    float al = 0.0f, ls = 0.0f;
    const f32x2* part = (const f32x2*)(ws + PART_OFF);
    for (int i = tid; i < NBLK; i += 256) {
        f32x2 p = part[i];
        al += p[0]; ls += p[1];
    }
#pragma unroll
    for (int off = 1; off < 64; off <<= 1) {
        al += __shfl_xor(al, off, 64);
        ls += __shfl_xor(ls, off, 64);
    }
    if (lane == 0) { sal[w] = al; sls[w] = ls; }
    __syncthreads();
    if (tid == 0) {
        const float inv = 1.0f / (float)E_TOT;
        out[E_TOT]     = (sal[0] + sal[1] + sal[2] + sal[3]) * inv;
        out[E_TOT + 1] = (sls[0] + sls[1] + sls[2] + sls[3]) * inv;
    }
}

extern "C" void kernel_launch(void* const* d_in, const int* in_sizes, int n_in,
                              void* d_out, int out_size, void* d_ws, size_t ws_size,
                              hipStream_t stream) {
    (void)in_sizes; (void)n_in; (void)out_size;
    const float* pos_source = (const float*)d_in[0];
    const float* pos_target = (const float*)d_in[1];
    const float* latents    = (const float*)d_in[2];
    const float* varr       = (const float*)d_in[3];
    const float* drop_mask  = (const float*)d_in[4];
    const float* W_in       = (const float*)d_in[5];
    const float* b_in       = (const float*)d_in[6];
    const float* W1         = (const float*)d_in[7];
    const float* b1         = (const float*)d_in[8];
    const float* W2         = (const float*)d_in[9];
    const float* b2         = (const float*)d_in[10];
    const float* W_out      = (const float*)d_in[11];
    const float* b_out      = (const float*)d_in[12];
    const int*   row        = (const int*)d_in[13];
    const int*   col        = (const int*)d_in[14];
    const int*   occ        = (const int*)d_in[15];
    float* out = (float*)d_out;
    char*  ws  = (char*)d_ws;

    const bool packed = (ws_size >= (size_t)WS_NEED);
    prep<<<29, 256, 0, stream>>>(W_in, b_in, W1, b1, W2, b2, W_out, b_out, ws);
    if (packed) {
        prep_pack<<<2048, 256, 0, stream>>>(latents, varr, ws);
        interp_main<true><<<NBLK, 256, 0, stream>>>(
            pos_source, pos_target, latents, varr, drop_mask,
            row, col, occ, out, ws);
    } else {
        interp_main<false><<<NBLK, 256, 0, stream>>>(
            pos_source, pos_target, latents, varr, drop_mask,
            row, col, occ, out, ws);
    }
    interp_finalize<<<1, 256, 0, stream>>>(ws, out);
}